// Round 13
// baseline (225.210 us; speedup 1.0000x reference)
//
#include <hip/hip_runtime.h>

typedef unsigned short u16;
typedef unsigned int u32;
typedef unsigned long long u64;
typedef __attribute__((ext_vector_type(8))) short short8;
typedef __attribute__((ext_vector_type(4))) float f32x4;

__device__ __forceinline__ u16 f2bf(float f) {
  u32 u = __builtin_bit_cast(u32, f);
  u += 0x7fffu + ((u >> 16) & 1u);
  return (u16)(u >> 16);
}
__device__ __forceinline__ u32 pk2bf(float a, float b) {
  return (u32)f2bf(a) | ((u32)f2bf(b) << 16);
}

__device__ __forceinline__ void async16(const void* g, void* l) {
  __builtin_amdgcn_global_load_lds(
      (const __attribute__((address_space(1))) u32*)g,
      (__attribute__((address_space(3))) u32*)l, 16, 0, 0);
}

// ---------------- merged prep: weight transposes + x transpose ------------
// grid 5120 = 768 (w_qkv^T) + 256 (w_out^T) + 4096 (x^T, 4 tiles/block).
// R8: merge -3.7 us. R11: 4 tiles/block -15 us. R13 (isolated from R12's
// bundle): 4 SEPARATE tile buffers -> all 4 loads in flight, ONE barrier
// per block (was 8). attn/proj are byte-identical to R11's verified forms.
// wt: in (K x N) f32 -> outT (N x K) bf16; rows n < scaleN get *0.125
//     (folds q-scale); perm: k within 64-block -> (k&15)*4+((k>>4)&3).
// xt: x (b,c,f,h,w) f32 -> XT[(b,spatial)*16+f][c] bf16.
__global__ __launch_bounds__(256) void k_prep(const float* __restrict__ x,
                                              const float* __restrict__ w_qkv,
                                              const float* __restrict__ w_out,
                                              u16* __restrict__ XT,
                                              u16* __restrict__ WQ,
                                              u16* __restrict__ WO) {
  __shared__ char smem[18432];
  int bid = blockIdx.x;
  const int t = threadIdx.x;
  if (bid < 1024) {
    // ---- weight transpose (block-uniform branch) ----
    const float* in;
    u16* outT;
    int N, scaleN, perm;
    if (bid < 768) { in = w_qkv; outT = WQ; N = 1536; scaleN = 512; perm = 0; }
    else { bid -= 768; in = w_out; outT = WO; N = 512; scaleN = 0; perm = 1; }
    const int K = 512;
    const int ntiles = N >> 5;
    const int nt = bid % ntiles, kt = bid / ntiles;
    const int n0 = nt << 5, k0 = kt << 5;
    float (*tile)[33] = (float(*)[33])smem;  // 4224 B, +1 pad: conflict-free
#pragma unroll
    for (int i = 0; i < 4; ++i) {
      const int e = t + i * 256, r = e >> 5, c = e & 31;  // r: k, c: n
      tile[c][r] = in[(size_t)(k0 + r) * N + n0 + c];
    }
    __syncthreads();
#pragma unroll
    for (int i = 0; i < 4; ++i) {
      const int e = t + i * 256, r = e >> 5, c = e & 31;  // r: n, c: k
      float v = tile[r][c];
      if (n0 + r < scaleN) v *= 0.125f;
      const int kcol = k0 + c;
      const int kp = perm ? ((kcol & ~63) | ((kcol & 15) << 2) | ((kcol >> 4) & 3))
                          : kcol;
      outT[(size_t)(n0 + r) * K + kp] = f2bf(v);
    }
  } else {
    // ---- x transpose: 4 m-tiles per block, 4 buffers, 1 barrier ----
    bid -= 1024;                       // 4096 = 32 planes x 8 mtg x 16 ct
    const int plane = bid & 31;        // b*16 + f
    const int rest = bid >> 5;
    const int mtg = rest & 7, ct = rest >> 3;
    const int bb = plane >> 4, f = plane & 15;
    const int c0 = ct << 5;
    float (*tile)[32][36] = (float(*)[32][36])smem;  // 4 x 4608 B
    const int lr = t >> 3, lc = t & 7;  // load: c-row, float4 chunk of m
    const int m = t >> 3, cc = t & 7;   // store: m-row, c-chunk of 4
#pragma unroll
    for (int i = 0; i < 4; ++i) {
      const int m0 = (mtg * 4 + i) << 5;
      const float4 v4 = *(const float4*)
          &x[((size_t)((bb * 512 + c0 + lr) * 16 + f)) * 1024 + m0 + lc * 4];
      *(float4*)&tile[i][lr][lc * 4] = v4;
    }
    __syncthreads();
#pragma unroll
    for (int i = 0; i < 4; ++i) {
      const int m0 = (mtg * 4 + i) << 5;
      union { u32 uu[2]; u64 q; } pk;
      pk.uu[0] = pk2bf(tile[i][cc * 4 + 0][m], tile[i][cc * 4 + 1][m]);
      pk.uu[1] = pk2bf(tile[i][cc * 4 + 2][m], tile[i][cc * 4 + 3][m]);
      *(u64*)&XT[((size_t)((bb * 1024 + m0 + m) * 16 + f)) * 512 + c0 + cc * 4] = pk.q;
    }
  }
}

// ---------------- fused QKV GEMM + MFMA attention -------------------------
// R11-verified form. Do not re-touch: R10 V-in-regs spilled (6.5x); R12
// two-pass vt4 (40960 B union) gained no occupancy (4 x 40960 = exactly
// 160 KiB does NOT fit — HW reserves LDS headroom) and cost +4.7 us.
// block = (128 rows = 8 sites x 16 f) x (one head: q|k|v 192 cols), K=512.
// bid = head*256 + mtile (hd-major; mt-major measured worse cold, R5).
// K-loop: BK=32, double-buffered, single barrier per step (T3 2-phase).
// Swizzle: rows are 64 B so the 128-B bank window spans TWO rows;
// chunk = quad ^ ((row>>1)&3) gives all 8 16-B slots, 2 lanes each (free).
struct A3St32 { u16 A[128][32]; u16 B[192][32]; };                 // 20480 B
struct A3At { u16 q[8][16][64]; u16 k[8][16][64]; u16 vt[8][64][16]; u16 pad[16]; };
union A3Sm { A3St32 st[2]; A3At at; };                             // 49184 B

__global__ __launch_bounds__(256) void k_qkv_attn(const u16* __restrict__ XT,
                                                  const u16* __restrict__ WQ,
                                                  const float* __restrict__ pos_bias,
                                                  u16* __restrict__ AO) {
  const int tid = threadIdx.x;
  const int w = tid >> 6, lane = tid & 63;
  const int c15 = lane & 15, quad = lane >> 4;
  const int bid = blockIdx.x;          // 2048 = 8 heads x 256 M-tiles
  const int hd = bid >> 8, m0 = (bid & 255) << 7;

  __shared__ A3Sm sm;

  // staging decomposition: 16 rows x 32 elems (64 B/row) per wave-call
  const int lr16 = lane >> 2, lc4 = lane & 3;

  // hoisted staging pointers (kk advances via constant byte offsets)
  const u16* aptr[2];
  const u16* bptr[3];
#pragma unroll
  for (int t2 = 0; t2 < 2; ++t2) {
    const int r = w * 32 + t2 * 16 + lr16;
    aptr[t2] = XT + (size_t)(m0 + r) * 512 + ((lc4 ^ ((r >> 1) & 3)) << 3);
  }
#pragma unroll
  for (int t2 = 0; t2 < 3; ++t2) {
    const int j = w * 48 + t2 * 16 + lr16;
    const int grow = (j >> 6) * 512 + hd * 64 + (j & 63);
    bptr[t2] = WQ + (size_t)grow * 512 + ((lc4 ^ ((j >> 1) & 3)) << 3);
  }

  f32x4 acc[3][8];
#pragma unroll
  for (int c = 0; c < 3; ++c)
#pragma unroll
    for (int mt = 0; mt < 8; ++mt) acc[c][mt] = f32x4{0.f, 0.f, 0.f, 0.f};

  // prologue: stage K-step 0 into buf 0
#pragma unroll
  for (int t2 = 0; t2 < 2; ++t2)
    async16(aptr[t2], &sm.st[0].A[w * 32 + t2 * 16][0]);
#pragma unroll
  for (int t2 = 0; t2 < 3; ++t2)
    async16(bptr[t2], &sm.st[0].B[w * 48 + t2 * 16][0]);
  __syncthreads();

#pragma unroll
  for (int kk = 0; kk < 16; ++kk) {
    const int cur = kk & 1, nxt = cur ^ 1;
    if (kk < 15) {
#pragma unroll
      for (int t2 = 0; t2 < 2; ++t2)
        async16(aptr[t2] + ((kk + 1) << 5), &sm.st[nxt].A[w * 32 + t2 * 16][0]);
#pragma unroll
      for (int t2 = 0; t2 < 3; ++t2)
        async16(bptr[t2] + ((kk + 1) << 5), &sm.st[nxt].B[w * 48 + t2 * 16][0]);
    }
    short8 af[8], bt[3];
#pragma unroll
    for (int mt = 0; mt < 8; ++mt) {
      const int row = mt * 16 + c15;
      const int swz = (quad ^ ((row >> 1) & 3)) << 3;
      af[mt] = *(const short8*)&sm.st[cur].A[row][swz];
    }
#pragma unroll
    for (int c = 0; c < 3; ++c) {
      const int row = c * 64 + w * 16 + c15;
      const int swz = (quad ^ ((row >> 1) & 3)) << 3;
      bt[c] = *(const short8*)&sm.st[cur].B[row][swz];
    }
#pragma unroll
    for (int c = 0; c < 3; ++c)
#pragma unroll
      for (int mt = 0; mt < 8; ++mt)
        acc[c][mt] = __builtin_amdgcn_mfma_f32_16x16x32_bf16(af[mt], bt[c], acc[c][mt], 0, 0, 0);
    __syncthreads();  // vmcnt(0) drain lands after 24 MFMAs + 11 ds_reads
  }
  // final barrier above: staging buffers dead; safe to overwrite via union

  // ---- write phase: acc -> q,k (chunk-swizzled scatter), vt (b64) --------
  const int dloc = w * 16 + c15;       // this wave's d-slice
  const int ch_b = dloc >> 3, dl = dloc & 7;
#pragma unroll
  for (int mt = 0; mt < 8; ++mt) {
#pragma unroll
    for (int r = 0; r < 4; ++r) {
      const int f = quad * 4 + r;
      const int sw = ((ch_b ^ (f & 7)) << 3) | dl;
      sm.at.q[mt][f][sw] = f2bf(acc[0][mt][r]);
      sm.at.k[mt][f][sw] = f2bf(acc[1][mt][r]);
    }
    union { u32 uu[2]; u64 q; } pv;
    pv.uu[0] = pk2bf(acc[2][mt][0], acc[2][mt][1]);
    pv.uu[1] = pk2bf(acc[2][mt][2], acc[2][mt][3]);
    *(u64*)&sm.at.vt[mt][dloc][quad * 4] = pv.q;
  }
  __syncthreads();

  float pb[4];
#pragma unroll
  for (int r = 0; r < 4; ++r)
    pb[r] = pos_bias[hd * 256 + (quad * 4 + r) * 16 + c15];

  // ---- attention: wave w owns sites 2w, 2w+1 (q/k/vt[s] wave-private now) -
  for (int sblk = 0; sblk < 2; ++sblk) {
    const int s = w * 2 + sblk;
    // S = Q @ K^T (one 16x16 tile, K=64 over 2 MFMA)
    f32x4 sacc = f32x4{0.f, 0.f, 0.f, 0.f};
#pragma unroll
    for (int h = 0; h < 2; ++h) {
      const int chunk = (((h << 2) + quad) ^ (c15 & 7)) << 3;
      const short8 aq = *(const short8*)&sm.at.q[s][c15][chunk];
      const short8 bk = *(const short8*)&sm.at.k[s][c15][chunk];
      sacc = __builtin_amdgcn_mfma_f32_16x16x32_bf16(aq, bk, sacc, 0, 0, 0);
    }
    // compiler fence: q[s] reads above must not sink below the P overlay
    asm volatile("" ::: "memory");
    // overlay P (u16[16][32], cols 16..31 zero) onto dead q[s]
    u16* lp = &sm.at.q[s][0][0];
#pragma unroll
    for (int e = 0; e < 4; ++e) lp[c15 * 32 + 16 + quad * 4 + e] = 0;
    // softmax rows i=quad*4+r across c15-lanes (bias added pre-max)
#pragma unroll
    for (int r = 0; r < 4; ++r) {
      float sv = sacc[r] + pb[r];
      float mx = sv;
      mx = fmaxf(mx, __shfl_xor(mx, 1));
      mx = fmaxf(mx, __shfl_xor(mx, 2));
      mx = fmaxf(mx, __shfl_xor(mx, 4));
      mx = fmaxf(mx, __shfl_xor(mx, 8));
      const float e = __expf(sv - mx);
      float sum = e;
      sum += __shfl_xor(sum, 1);
      sum += __shfl_xor(sum, 2);
      sum += __shfl_xor(sum, 4);
      sum += __shfl_xor(sum, 8);
      lp[(quad * 4 + r) * 32 + c15] = f2bf(e / sum);
    }
    // compiler fence: P writes above must complete before the ap read below
    asm volatile("" ::: "memory");
    // PV: A = P (K padded to 32, cols 16..31 exactly 0), B = V via vt rows=d.
    // For quad>=2 (k=16..31) A is zero, so clamp the vt read to a valid
    // in-row chunk ((quad&1)*8): contributes 0, never touches OOB/uninit LDS.
    const short8 ap = *(const short8*)&lp[c15 * 32 + quad * 8];
    f32x4 oacc[4];
#pragma unroll
    for (int t = 0; t < 4; ++t) {
      const short8 bv = *(const short8*)&sm.at.vt[s][t * 16 + c15][(quad & 1) * 8];
      oacc[t] = __builtin_amdgcn_mfma_f32_16x16x32_bf16(ap, bv, f32x4{0.f, 0.f, 0.f, 0.f}, 0, 0, 0);
    }
    // store: out[i=quad*4+r][d=t*16+c15] -> AO col hd*64 + pi(d), pi(d)=c15*4+t
    const int s_g = (m0 >> 4) + s;
    const int bb = s_g >> 10, sp = s_g & 1023;
#pragma unroll
    for (int r = 0; r < 4; ++r) {
      union { u32 uu[2]; uint2 v; } pk;
      pk.uu[0] = pk2bf(oacc[0][r], oacc[1][r]);
      pk.uu[1] = pk2bf(oacc[2][r], oacc[3][r]);
      *(uint2*)(AO + ((size_t)(bb * 16384 + (quad * 4 + r) * 1024 + sp)) * 512 +
                hd * 64 + c15 * 4) = pk.v;
    }
  }
}

// ---------------- out projection GEMM + direct store ----------------------
// K-loop: round-0 baseline form (BK=64, 8 K-steps, 2 barriers/step).
// Epilogue: DIRECT f32x4 stores (R9: -9.2 us vs LDS C-transpose).
struct K2St { u16 A[128][64]; u16 B[128][64]; };                   // 32768 B

__global__ __launch_bounds__(256) void k_proj(const u16* __restrict__ AO,
                                              const u16* __restrict__ WO,
                                              float* __restrict__ out) {
  const int tid = threadIdx.x, w = tid >> 6, lane = tid & 63;
  const int c15 = lane & 15, quad = lane >> 4;
  const int bid = blockIdx.x;          // 1024 = 4 n-tiles x 256 m-tiles
  const int mb = bid & 255, nb = bid >> 8;  // A-tile reusers share an XCD
  const int m0 = mb << 7, n0 = nb << 7;
  const int b = m0 >> 14, mloc = m0 & 16383;
  __shared__ K2St sm;
  f32x4 acc[8][2];
#pragma unroll
  for (int mt = 0; mt < 8; ++mt) {
    acc[mt][0] = f32x4{0.f, 0.f, 0.f, 0.f};
    acc[mt][1] = f32x4{0.f, 0.f, 0.f, 0.f};
  }
  const int lr = lane >> 3, lcb = lane & 7;
  const u16* aptr[4];
  const u16* bptr[4];
#pragma unroll
  for (int t2 = 0; t2 < 4; ++t2) {
    const int r = w * 32 + t2 * 8 + lr;
    const int sw = (lcb ^ (r & 7)) << 3;
    aptr[t2] = AO + (size_t)(m0 + r) * 512 + sw;
    bptr[t2] = WO + (size_t)(n0 + r) * 512 + sw;
  }
#pragma unroll
  for (int kk = 0; kk < 8; ++kk) {
    __syncthreads();
#pragma unroll
    for (int t2 = 0; t2 < 4; ++t2) {
      async16(aptr[t2] + (kk << 6), &sm.A[w * 32 + t2 * 8][0]);
      async16(bptr[t2] + (kk << 6), &sm.B[w * 32 + t2 * 8][0]);
    }
    __syncthreads();
#pragma unroll
    for (int half = 0; half < 2; ++half) {
      short8 af[8], bt[2];
#pragma unroll
      for (int mt = 0; mt < 8; ++mt) {
        const int row = mt * 16 + c15;
        const int swz = (((half << 2) + quad) ^ (row & 7)) << 3;
        af[mt] = *(const short8*)&sm.A[row][swz];
      }
#pragma unroll
      for (int nt = 0; nt < 2; ++nt) {
        const int row = w * 32 + nt * 16 + c15;
        const int swz = (((half << 2) + quad) ^ (row & 7)) << 3;
        bt[nt] = *(const short8*)&sm.B[row][swz];
      }
#pragma unroll
      for (int mt = 0; mt < 8; ++mt) {
        acc[mt][0] = __builtin_amdgcn_mfma_f32_16x16x32_bf16(af[mt], bt[0], acc[mt][0], 0, 0, 0);
        acc[mt][1] = __builtin_amdgcn_mfma_f32_16x16x32_bf16(af[mt], bt[1], acc[mt][1], 0, 0, 0);
      }
    }
  }
  // epilogue: registers only — no barrier needed after final K-step compute
  float* const obase = out + (size_t)b * 512 * 16384 + mloc + quad * 4;
#pragma unroll
  for (int nt = 0; nt < 2; ++nt) {
    const int ch = n0 + w * 32 + nt * 16 + c15;
    float* const orow = obase + (size_t)ch * 16384;
#pragma unroll
    for (int mt = 0; mt < 8; ++mt)
      *(f32x4*)&orow[mt * 16] = acc[mt][nt];
  }
}

extern "C" void kernel_launch(void* const* d_in, const int* in_sizes, int n_in,
                              void* d_out, int out_size, void* d_ws, size_t ws_size,
                              hipStream_t stream) {
  const float* x = (const float*)d_in[0];
  const float* pos_bias = (const float*)d_in[1];
  const float* w_qkv = (const float*)d_in[2];
  const float* w_out = (const float*)d_in[3];
  float* out = (float*)d_out;
  char* ws = (char*)d_ws;
  // ws layout (bytes): XT 33554432 | AO 33554432 | WQ 1572864 | WO 524288
  u16* XT = (u16*)(ws);
  u16* AO = (u16*)(ws + (size_t)33554432);
  u16* WQ = (u16*)(ws + (size_t)67108864);
  u16* WO = (u16*)(ws + (size_t)68681728);

  hipLaunchKernelGGL(k_prep, dim3(5120), dim3(256), 0, stream, x, w_qkv, w_out, XT, WQ, WO);
  hipLaunchKernelGGL(k_qkv_attn, dim3(2048), dim3(256), 0, stream, XT, WQ, pos_bias, AO);
  hipLaunchKernelGGL(k_proj, dim3(1024), dim3(256), 0, stream, AO, WO, out);
}

// Round 14
// 212.724 us; speedup vs baseline: 1.0587x; 1.0587x over previous
//
#include <hip/hip_runtime.h>

typedef unsigned short u16;
typedef unsigned int u32;
typedef unsigned long long u64;
typedef __attribute__((ext_vector_type(8))) short short8;
typedef __attribute__((ext_vector_type(4))) float f32x4;

__device__ __forceinline__ u16 f2bf(float f) {
  u32 u = __builtin_bit_cast(u32, f);
  u += 0x7fffu + ((u >> 16) & 1u);
  return (u16)(u >> 16);
}
__device__ __forceinline__ u32 pk2bf(float a, float b) {
  return (u32)f2bf(a) | ((u32)f2bf(b) << 16);
}

__device__ __forceinline__ void async16(const void* g, void* l) {
  __builtin_amdgcn_global_load_lds(
      (const __attribute__((address_space(1))) u32*)g,
      (__attribute__((address_space(3))) u32*)l, 16, 0, 0);
}

// ---------------- merged prep: weight transposes + x transpose ------------
// grid 5120 = 768 (w_qkv^T) + 256 (w_out^T) + 4096 (x^T, 4 tiles/block).
// R8: merge -3.7 us. R11: 4 tiles/block loop form -15 us (this version).
// R13 measured the 4-separate-buffer/1-barrier variant at +12 us — the
// looped single-buffer form lets iteration-i stores overlap iteration-i+1
// loads wave-by-wave; keep THIS form.
// wt: in (K x N) f32 -> outT (N x K) bf16; rows n < scaleN get *0.125
//     (folds q-scale); perm: k within 64-block -> (k&15)*4+((k>>4)&3).
// xt: x (b,c,f,h,w) f32 -> XT[(b,spatial)*16+f][c] bf16.
__global__ __launch_bounds__(256) void k_prep(const float* __restrict__ x,
                                              const float* __restrict__ w_qkv,
                                              const float* __restrict__ w_out,
                                              u16* __restrict__ XT,
                                              u16* __restrict__ WQ,
                                              u16* __restrict__ WO) {
  __shared__ char smem[4608];
  int bid = blockIdx.x;
  const int t = threadIdx.x;
  if (bid < 1024) {
    // ---- weight transpose (block-uniform branch) ----
    const float* in;
    u16* outT;
    int N, scaleN, perm;
    if (bid < 768) { in = w_qkv; outT = WQ; N = 1536; scaleN = 512; perm = 0; }
    else { bid -= 768; in = w_out; outT = WO; N = 512; scaleN = 0; perm = 1; }
    const int K = 512;
    const int ntiles = N >> 5;
    const int nt = bid % ntiles, kt = bid / ntiles;
    const int n0 = nt << 5, k0 = kt << 5;
    float (*tile)[33] = (float(*)[33])smem;  // 4224 B, +1 pad: conflict-free
#pragma unroll
    for (int i = 0; i < 4; ++i) {
      const int e = t + i * 256, r = e >> 5, c = e & 31;  // r: k, c: n
      tile[c][r] = in[(size_t)(k0 + r) * N + n0 + c];
    }
    __syncthreads();
#pragma unroll
    for (int i = 0; i < 4; ++i) {
      const int e = t + i * 256, r = e >> 5, c = e & 31;  // r: n, c: k
      float v = tile[r][c];
      if (n0 + r < scaleN) v *= 0.125f;
      const int kcol = k0 + c;
      const int kp = perm ? ((kcol & ~63) | ((kcol & 15) << 2) | ((kcol >> 4) & 3))
                          : kcol;
      outT[(size_t)(n0 + r) * K + kp] = f2bf(v);
    }
  } else {
    // ---- x transpose: 4 consecutive m-tiles per block ----
    bid -= 1024;                       // 4096 = 32 planes x 8 mtg x 16 ct
    const int plane = bid & 31;        // b*16 + f
    const int rest = bid >> 5;
    const int mtg = rest & 7, ct = rest >> 3;
    const int bb = plane >> 4, f = plane & 15;
    const int c0 = ct << 5;
    float (*tile)[36] = (float(*)[36])smem;  // 4608 B
    const int lr = t >> 3, lc = t & 7;  // load: c-row, float4 chunk of m
    const int m = t >> 3, cc = t & 7;   // store: m-row, c-chunk of 4
#pragma unroll
    for (int i = 0; i < 4; ++i) {
      const int m0 = (mtg * 4 + i) << 5;
      const float4 v4 = *(const float4*)
          &x[((size_t)((bb * 512 + c0 + lr) * 16 + f)) * 1024 + m0 + lc * 4];
      *(float4*)&tile[lr][lc * 4] = v4;
      __syncthreads();
      union { u32 uu[2]; u64 q; } pk;
      pk.uu[0] = pk2bf(tile[cc * 4 + 0][m], tile[cc * 4 + 1][m]);
      pk.uu[1] = pk2bf(tile[cc * 4 + 2][m], tile[cc * 4 + 3][m]);
      *(u64*)&XT[((size_t)((bb * 1024 + m0 + m) * 16 + f)) * 512 + c0 + cc * 4] = pk.q;
      __syncthreads();                  // tile reused next iteration
    }
  }
}

// ---------------- fused QKV GEMM + MFMA attention -------------------------
// R9/R11-verified form. Do not re-touch: R10 V-in-regs spilled (6.5x); R12
// two-pass vt4 (40960 B union) gained no occupancy (4 x 40960 = exactly
// 160 KiB does NOT fit — HW reserves LDS headroom) and cost +4.7 us.
// block = (128 rows = 8 sites x 16 f) x (one head: q|k|v 192 cols), K=512.
// bid = head*256 + mtile (hd-major; mt-major measured worse cold, R5).
// K-loop: BK=32, double-buffered, single barrier per step (T3 2-phase).
// Swizzle: rows are 64 B so the 128-B bank window spans TWO rows;
// chunk = quad ^ ((row>>1)&3) gives all 8 16-B slots, 2 lanes each (free).
struct A3St32 { u16 A[128][32]; u16 B[192][32]; };                 // 20480 B
struct A3At { u16 q[8][16][64]; u16 k[8][16][64]; u16 vt[8][64][16]; u16 pad[16]; };
union A3Sm { A3St32 st[2]; A3At at; };                             // 49184 B

__global__ __launch_bounds__(256) void k_qkv_attn(const u16* __restrict__ XT,
                                                  const u16* __restrict__ WQ,
                                                  const float* __restrict__ pos_bias,
                                                  u16* __restrict__ AO) {
  const int tid = threadIdx.x;
  const int w = tid >> 6, lane = tid & 63;
  const int c15 = lane & 15, quad = lane >> 4;
  const int bid = blockIdx.x;          // 2048 = 8 heads x 256 M-tiles
  const int hd = bid >> 8, m0 = (bid & 255) << 7;

  __shared__ A3Sm sm;

  // staging decomposition: 16 rows x 32 elems (64 B/row) per wave-call
  const int lr16 = lane >> 2, lc4 = lane & 3;

  // hoisted staging pointers (kk advances via constant byte offsets)
  const u16* aptr[2];
  const u16* bptr[3];
#pragma unroll
  for (int t2 = 0; t2 < 2; ++t2) {
    const int r = w * 32 + t2 * 16 + lr16;
    aptr[t2] = XT + (size_t)(m0 + r) * 512 + ((lc4 ^ ((r >> 1) & 3)) << 3);
  }
#pragma unroll
  for (int t2 = 0; t2 < 3; ++t2) {
    const int j = w * 48 + t2 * 16 + lr16;
    const int grow = (j >> 6) * 512 + hd * 64 + (j & 63);
    bptr[t2] = WQ + (size_t)grow * 512 + ((lc4 ^ ((j >> 1) & 3)) << 3);
  }

  f32x4 acc[3][8];
#pragma unroll
  for (int c = 0; c < 3; ++c)
#pragma unroll
    for (int mt = 0; mt < 8; ++mt) acc[c][mt] = f32x4{0.f, 0.f, 0.f, 0.f};

  // prologue: stage K-step 0 into buf 0
#pragma unroll
  for (int t2 = 0; t2 < 2; ++t2)
    async16(aptr[t2], &sm.st[0].A[w * 32 + t2 * 16][0]);
#pragma unroll
  for (int t2 = 0; t2 < 3; ++t2)
    async16(bptr[t2], &sm.st[0].B[w * 48 + t2 * 16][0]);
  __syncthreads();

#pragma unroll
  for (int kk = 0; kk < 16; ++kk) {
    const int cur = kk & 1, nxt = cur ^ 1;
    if (kk < 15) {
#pragma unroll
      for (int t2 = 0; t2 < 2; ++t2)
        async16(aptr[t2] + ((kk + 1) << 5), &sm.st[nxt].A[w * 32 + t2 * 16][0]);
#pragma unroll
      for (int t2 = 0; t2 < 3; ++t2)
        async16(bptr[t2] + ((kk + 1) << 5), &sm.st[nxt].B[w * 48 + t2 * 16][0]);
    }
    short8 af[8], bt[3];
#pragma unroll
    for (int mt = 0; mt < 8; ++mt) {
      const int row = mt * 16 + c15;
      const int swz = (quad ^ ((row >> 1) & 3)) << 3;
      af[mt] = *(const short8*)&sm.st[cur].A[row][swz];
    }
#pragma unroll
    for (int c = 0; c < 3; ++c) {
      const int row = c * 64 + w * 16 + c15;
      const int swz = (quad ^ ((row >> 1) & 3)) << 3;
      bt[c] = *(const short8*)&sm.st[cur].B[row][swz];
    }
#pragma unroll
    for (int c = 0; c < 3; ++c)
#pragma unroll
      for (int mt = 0; mt < 8; ++mt)
        acc[c][mt] = __builtin_amdgcn_mfma_f32_16x16x32_bf16(af[mt], bt[c], acc[c][mt], 0, 0, 0);
    __syncthreads();  // vmcnt(0) drain lands after 24 MFMAs + 11 ds_reads
  }
  // final barrier above: staging buffers dead; safe to overwrite via union

  // ---- write phase: acc -> q,k (chunk-swizzled scatter), vt (b64) --------
  const int dloc = w * 16 + c15;       // this wave's d-slice
  const int ch_b = dloc >> 3, dl = dloc & 7;
#pragma unroll
  for (int mt = 0; mt < 8; ++mt) {
#pragma unroll
    for (int r = 0; r < 4; ++r) {
      const int f = quad * 4 + r;
      const int sw = ((ch_b ^ (f & 7)) << 3) | dl;
      sm.at.q[mt][f][sw] = f2bf(acc[0][mt][r]);
      sm.at.k[mt][f][sw] = f2bf(acc[1][mt][r]);
    }
    union { u32 uu[2]; u64 q; } pv;
    pv.uu[0] = pk2bf(acc[2][mt][0], acc[2][mt][1]);
    pv.uu[1] = pk2bf(acc[2][mt][2], acc[2][mt][3]);
    *(u64*)&sm.at.vt[mt][dloc][quad * 4] = pv.q;
  }
  __syncthreads();

  float pb[4];
#pragma unroll
  for (int r = 0; r < 4; ++r)
    pb[r] = pos_bias[hd * 256 + (quad * 4 + r) * 16 + c15];

  // ---- attention: wave w owns sites 2w, 2w+1 (q/k/vt[s] wave-private now) -
  for (int sblk = 0; sblk < 2; ++sblk) {
    const int s = w * 2 + sblk;
    // S = Q @ K^T (one 16x16 tile, K=64 over 2 MFMA)
    f32x4 sacc = f32x4{0.f, 0.f, 0.f, 0.f};
#pragma unroll
    for (int h = 0; h < 2; ++h) {
      const int chunk = (((h << 2) + quad) ^ (c15 & 7)) << 3;
      const short8 aq = *(const short8*)&sm.at.q[s][c15][chunk];
      const short8 bk = *(const short8*)&sm.at.k[s][c15][chunk];
      sacc = __builtin_amdgcn_mfma_f32_16x16x32_bf16(aq, bk, sacc, 0, 0, 0);
    }
    // compiler fence: q[s] reads above must not sink below the P overlay
    asm volatile("" ::: "memory");
    // overlay P (u16[16][32], cols 16..31 zero) onto dead q[s]
    u16* lp = &sm.at.q[s][0][0];
#pragma unroll
    for (int e = 0; e < 4; ++e) lp[c15 * 32 + 16 + quad * 4 + e] = 0;
    // softmax rows i=quad*4+r across c15-lanes (bias added pre-max)
#pragma unroll
    for (int r = 0; r < 4; ++r) {
      float sv = sacc[r] + pb[r];
      float mx = sv;
      mx = fmaxf(mx, __shfl_xor(mx, 1));
      mx = fmaxf(mx, __shfl_xor(mx, 2));
      mx = fmaxf(mx, __shfl_xor(mx, 4));
      mx = fmaxf(mx, __shfl_xor(mx, 8));
      const float e = __expf(sv - mx);
      float sum = e;
      sum += __shfl_xor(sum, 1);
      sum += __shfl_xor(sum, 2);
      sum += __shfl_xor(sum, 4);
      sum += __shfl_xor(sum, 8);
      lp[(quad * 4 + r) * 32 + c15] = f2bf(e / sum);
    }
    // compiler fence: P writes above must complete before the ap read below
    asm volatile("" ::: "memory");
    // PV: A = P (K padded to 32, cols 16..31 exactly 0), B = V via vt rows=d.
    // For quad>=2 (k=16..31) A is zero, so clamp the vt read to a valid
    // in-row chunk ((quad&1)*8): contributes 0, never touches OOB/uninit LDS.
    const short8 ap = *(const short8*)&lp[c15 * 32 + quad * 8];
    f32x4 oacc[4];
#pragma unroll
    for (int t = 0; t < 4; ++t) {
      const short8 bv = *(const short8*)&sm.at.vt[s][t * 16 + c15][(quad & 1) * 8];
      oacc[t] = __builtin_amdgcn_mfma_f32_16x16x32_bf16(ap, bv, f32x4{0.f, 0.f, 0.f, 0.f}, 0, 0, 0);
    }
    // store: out[i=quad*4+r][d=t*16+c15] -> AO col hd*64 + pi(d), pi(d)=c15*4+t
    const int s_g = (m0 >> 4) + s;
    const int bb = s_g >> 10, sp = s_g & 1023;
#pragma unroll
    for (int r = 0; r < 4; ++r) {
      union { u32 uu[2]; uint2 v; } pk;
      pk.uu[0] = pk2bf(oacc[0][r], oacc[1][r]);
      pk.uu[1] = pk2bf(oacc[2][r], oacc[3][r]);
      *(uint2*)(AO + ((size_t)(bb * 16384 + (quad * 4 + r) * 1024 + sp)) * 512 +
                hd * 64 + c15 * 4) = pk.v;
    }
  }
}

// ---------------- out projection GEMM + direct store ----------------------
// K-loop: round-0 baseline form (BK=64, 8 K-steps, 2 barriers/step).
// Epilogue: DIRECT f32x4 stores (R9: -9.2 us vs LDS C-transpose).
struct K2St { u16 A[128][64]; u16 B[128][64]; };                   // 32768 B

__global__ __launch_bounds__(256) void k_proj(const u16* __restrict__ AO,
                                              const u16* __restrict__ WO,
                                              float* __restrict__ out) {
  const int tid = threadIdx.x, w = tid >> 6, lane = tid & 63;
  const int c15 = lane & 15, quad = lane >> 4;
  const int bid = blockIdx.x;          // 1024 = 4 n-tiles x 256 m-tiles
  const int mb = bid & 255, nb = bid >> 8;  // A-tile reusers share an XCD
  const int m0 = mb << 7, n0 = nb << 7;
  const int b = m0 >> 14, mloc = m0 & 16383;
  __shared__ K2St sm;
  f32x4 acc[8][2];
#pragma unroll
  for (int mt = 0; mt < 8; ++mt) {
    acc[mt][0] = f32x4{0.f, 0.f, 0.f, 0.f};
    acc[mt][1] = f32x4{0.f, 0.f, 0.f, 0.f};
  }
  const int lr = lane >> 3, lcb = lane & 7;
  const u16* aptr[4];
  const u16* bptr[4];
#pragma unroll
  for (int t2 = 0; t2 < 4; ++t2) {
    const int r = w * 32 + t2 * 8 + lr;
    const int sw = (lcb ^ (r & 7)) << 3;
    aptr[t2] = AO + (size_t)(m0 + r) * 512 + sw;
    bptr[t2] = WO + (size_t)(n0 + r) * 512 + sw;
  }
#pragma unroll
  for (int kk = 0; kk < 8; ++kk) {
    __syncthreads();
#pragma unroll
    for (int t2 = 0; t2 < 4; ++t2) {
      async16(aptr[t2] + (kk << 6), &sm.A[w * 32 + t2 * 8][0]);
      async16(bptr[t2] + (kk << 6), &sm.B[w * 32 + t2 * 8][0]);
    }
    __syncthreads();
#pragma unroll
    for (int half = 0; half < 2; ++half) {
      short8 af[8], bt[2];
#pragma unroll
      for (int mt = 0; mt < 8; ++mt) {
        const int row = mt * 16 + c15;
        const int swz = (((half << 2) + quad) ^ (row & 7)) << 3;
        af[mt] = *(const short8*)&sm.A[row][swz];
      }
#pragma unroll
      for (int nt = 0; nt < 2; ++nt) {
        const int row = w * 32 + nt * 16 + c15;
        const int swz = (((half << 2) + quad) ^ (row & 7)) << 3;
        bt[nt] = *(const short8*)&sm.B[row][swz];
      }
#pragma unroll
      for (int mt = 0; mt < 8; ++mt) {
        acc[mt][0] = __builtin_amdgcn_mfma_f32_16x16x32_bf16(af[mt], bt[0], acc[mt][0], 0, 0, 0);
        acc[mt][1] = __builtin_amdgcn_mfma_f32_16x16x32_bf16(af[mt], bt[1], acc[mt][1], 0, 0, 0);
      }
    }
  }
  // epilogue: registers only — no barrier needed after final K-step compute
  float* const obase = out + (size_t)b * 512 * 16384 + mloc + quad * 4;
#pragma unroll
  for (int nt = 0; nt < 2; ++nt) {
    const int ch = n0 + w * 32 + nt * 16 + c15;
    float* const orow = obase + (size_t)ch * 16384;
#pragma unroll
    for (int mt = 0; mt < 8; ++mt)
      *(f32x4*)&orow[mt * 16] = acc[mt][nt];
  }
}

extern "C" void kernel_launch(void* const* d_in, const int* in_sizes, int n_in,
                              void* d_out, int out_size, void* d_ws, size_t ws_size,
                              hipStream_t stream) {
  const float* x = (const float*)d_in[0];
  const float* pos_bias = (const float*)d_in[1];
  const float* w_qkv = (const float*)d_in[2];
  const float* w_out = (const float*)d_in[3];
  float* out = (float*)d_out;
  char* ws = (char*)d_ws;
  // ws layout (bytes): XT 33554432 | AO 33554432 | WQ 1572864 | WO 524288
  u16* XT = (u16*)(ws);
  u16* AO = (u16*)(ws + (size_t)33554432);
  u16* WQ = (u16*)(ws + (size_t)67108864);
  u16* WO = (u16*)(ws + (size_t)68681728);

  hipLaunchKernelGGL(k_prep, dim3(5120), dim3(256), 0, stream, x, w_qkv, w_out, XT, WQ, WO);
  hipLaunchKernelGGL(k_qkv_attn, dim3(2048), dim3(256), 0, stream, XT, WQ, pos_bias, AO);
  hipLaunchKernelGGL(k_proj, dim3(1024), dim3(256), 0, stream, AO, WO, out);
}